// Round 1
// baseline (670.675 us; speedup 1.0000x reference)
//
#include <hip/hip_runtime.h>

typedef unsigned short u16;
typedef unsigned int u32;
typedef float f32x4 __attribute__((ext_vector_type(4)));
typedef __bf16 bf16x8 __attribute__((ext_vector_type(8)));
typedef unsigned short u16x8 __attribute__((ext_vector_type(8)));
typedef unsigned short u16x4 __attribute__((ext_vector_type(4)));

#define DEV static __device__ __forceinline__

DEV u16 f2bf(float f) {
  union { float f; u32 u; } x; x.f = f;
  u32 r = x.u + 0x7FFFu + ((x.u >> 16) & 1u);
  return (u16)(r >> 16);
}

DEV f32x4 mfma16(bf16x8 a, bf16x8 b, f32x4 c) {
  return __builtin_amdgcn_mfma_f32_16x16x32_bf16(a, b, c, 0, 0, 0);
}

// ---- fp32 -> bf16 convert (weights) ----
__global__ __launch_bounds__(256) void k_f2bf(const float* __restrict__ in,
                                              u16* __restrict__ out, int n) {
  int i = (blockIdx.x * 256 + threadIdx.x) * 4;
  if (i >= n) return;
  f32x4 v = *(const f32x4*)(in + i);
  u16x4 o;
#pragma unroll
  for (int j = 0; j < 4; ++j) o[j] = f2bf(v[j]);
  *(u16x4*)(out + i) = o;
}

// ---- generic BT-GEMM: C[m][n] = scale * sum_k A[m][k] * B[n][k] (+ bias[n]) ----
// A: fp32 or bf16(u16), row-major lda; B: bf16 row-major ldb.
// OUT_MODE 0: fp32 row-major (ldc, batch sC)
// OUT_MODE 1: bf16 split-head: row=(b*2048+s), col=(h*64+d) -> [(b*16+h)*2048+s]*64+d
// OUT_MODE 2: bf16 PV-merge: z=(b*16+h), out[(b*2048+row)*1024 + h*64 + col]
template<int BM, int BN, bool A_F32, int OUT_MODE, bool HAS_BIAS>
__global__ __launch_bounds__(256) void k_gemm_bt(
    const void* __restrict__ Aptr, const u16* __restrict__ Bptr,
    const float* __restrict__ bias, void* __restrict__ Cptr,
    int K, int lda, int ldb, int ldc,
    long sA, long sB, long sC, float scale)
{
  constexpr int WM = BM / 64, WN = BN / 64;
  static_assert(WM * WN == 4, "4 waves");
  constexpr int LDSK = 40;  // 32 + 8 pad (bank-conflict break), keeps 16B align
  __shared__ u16 a_lds[BM * LDSK];
  __shared__ u16 b_lds[BN * LDSK];

  const int t = threadIdx.x;
  const int lane = t & 63, wid = t >> 6;
  const int wm = wid % WM, wn = wid / WM;
  const long a_off = (long)blockIdx.z * sA + (long)blockIdx.x * BM * lda;
  const long b_off = (long)blockIdx.z * sB + (long)blockIdx.y * BN * ldb;
  const float* __restrict__ Af = (const float*)Aptr;
  const u16*  __restrict__ Ab = (const u16*)Aptr;

  f32x4 acc[4][4] = {};
  const int fr = lane & 15, kq = (lane >> 4) * 8;

  for (int kt = 0; kt < K; kt += 32) {
    // stage A tile BMx32 (convert fp32->bf16 if needed)
#pragma unroll
    for (int i = 0; i < BM / 64; ++i) {
      int idx = t + i * 256;
      int row = idx >> 2, k0 = (idx & 3) * 8;
      long g = a_off + (long)row * lda + kt + k0;
      u16x8 stg;
      if (A_F32) {
        f32x4 v0 = *(const f32x4*)(Af + g);
        f32x4 v1 = *(const f32x4*)(Af + g + 4);
#pragma unroll
        for (int j = 0; j < 4; ++j) { stg[j] = f2bf(v0[j]); stg[4 + j] = f2bf(v1[j]); }
      } else {
        stg = *(const u16x8*)(Ab + g);
      }
      *(u16x8*)&a_lds[row * LDSK + k0] = stg;
    }
    // stage B tile BNx32 (always bf16)
#pragma unroll
    for (int i = 0; i < BN / 64; ++i) {
      int idx = t + i * 256;
      int row = idx >> 2, k0 = (idx & 3) * 8;
      long g = b_off + (long)row * ldb + kt + k0;
      *(u16x8*)&b_lds[row * LDSK + k0] = *(const u16x8*)(Bptr + g);
    }
    __syncthreads();

    bf16x8 af[4], bf[4];
#pragma unroll
    for (int mi = 0; mi < 4; ++mi)
      af[mi] = *(const bf16x8*)&a_lds[(wm * 64 + mi * 16 + fr) * LDSK + kq];
#pragma unroll
    for (int ni = 0; ni < 4; ++ni)
      bf[ni] = *(const bf16x8*)&b_lds[(wn * 64 + ni * 16 + fr) * LDSK + kq];
#pragma unroll
    for (int mi = 0; mi < 4; ++mi)
#pragma unroll
      for (int ni = 0; ni < 4; ++ni)
        acc[mi][ni] = mfma16(af[mi], bf[ni], acc[mi][ni]);
    __syncthreads();
  }

  // epilogue: C/D frag mapping col=lane&15, row=(lane>>4)*4+reg  [m89-verified]
  const int r4 = (lane >> 4) * 4, cc = lane & 15;
#pragma unroll
  for (int mi = 0; mi < 4; ++mi)
#pragma unroll
  for (int ni = 0; ni < 4; ++ni)
#pragma unroll
  for (int rg = 0; rg < 4; ++rg) {
    int row = blockIdx.x * BM + wm * 64 + mi * 16 + r4 + rg;
    int col = blockIdx.y * BN + wn * 64 + ni * 16 + cc;
    float v = acc[mi][ni][rg] * scale;
    if (HAS_BIAS) v += bias[col];
    if (OUT_MODE == 0) {
      ((float*)Cptr)[(long)blockIdx.z * sC + (long)row * ldc + col] = v;
    } else if (OUT_MODE == 1) {
      int b = row >> 11, s = row & 2047, h = col >> 6, d = col & 63;
      ((u16*)Cptr)[(((long)(b * 16 + h) * 2048 + s) << 6) + d] = f2bf(v);
    } else {
      int b = blockIdx.z >> 4, h = blockIdx.z & 15;
      ((u16*)Cptr)[((long)(b * 2048 + row) << 10) + h * 64 + col] = f2bf(v);
    }
  }
}

// ---- per-head V transpose: (bh, S=2048, 64) -> (bh, 64, S=2048), bf16 ----
__global__ __launch_bounds__(256) void k_transpose_v(const u16* __restrict__ vp,
                                                     u16* __restrict__ vpt) {
  __shared__ u16 tile[64][72];
  const int t = threadIdx.x;
  const long base = (long)blockIdx.y * (2048 * 64);
  const int s0 = blockIdx.x * 64;
#pragma unroll
  for (int i = 0; i < 2; ++i) {
    int idx = t + i * 256;
    int s = idx >> 3, c = (idx & 7) * 8;
    u16x8 v = *(const u16x8*)&vp[base + (long)(s0 + s) * 64 + c];
    *(u16x8*)&tile[s][c] = v;
  }
  __syncthreads();
  const long obase = (long)blockIdx.y * (64 * 2048);
#pragma unroll
  for (int i = 0; i < 2; ++i) {
    int idx = t + i * 256;
    int d = idx >> 3, c = (idx & 7) * 8;
    u16x8 v;
#pragma unroll
    for (int j = 0; j < 8; ++j) v[j] = tile[c + j][d];
    *(u16x8*)&vpt[obase + (long)d * 2048 + s0 + c] = v;
  }
}

// ---- row softmax in place: 65536 rows x 2048 f32; 1 wave per row ----
__global__ __launch_bounds__(256) void k_softmax(float* __restrict__ attn) {
  const int wid = threadIdx.x >> 6, lane = threadIdx.x & 63;
  const long row = (long)blockIdx.x * 4 + wid;
  float* p = attn + row * 2048;
  f32x4 v[8];
#pragma unroll
  for (int j = 0; j < 8; ++j) v[j] = *(const f32x4*)(p + ((j << 6) + lane) * 4);
  float mx = -1e30f;
#pragma unroll
  for (int j = 0; j < 8; ++j)
#pragma unroll
    for (int e = 0; e < 4; ++e) mx = fmaxf(mx, v[j][e]);
#pragma unroll
  for (int off = 32; off; off >>= 1) mx = fmaxf(mx, __shfl_xor(mx, off));
  float s = 0.f;
#pragma unroll
  for (int j = 0; j < 8; ++j)
#pragma unroll
    for (int e = 0; e < 4; ++e) { float ev = __expf(v[j][e] - mx); v[j][e] = ev; s += ev; }
#pragma unroll
  for (int off = 32; off; off >>= 1) s += __shfl_xor(s, off);
  const float inv = 1.0f / s;
#pragma unroll
  for (int j = 0; j < 8; ++j) {
    v[j] *= inv;
    *(f32x4*)(p + ((j << 6) + lane) * 4) = v[j];
  }
}

extern "C" void kernel_launch(void* const* d_in, const int* in_sizes, int n_in,
                              void* d_out, int out_size, void* d_ws, size_t ws_size,
                              hipStream_t stream) {
  const float* Q  = (const float*)d_in[0];
  const float* Kx = (const float*)d_in[1];
  const float* V  = (const float*)d_in[2];
  const float* Wq = (const float*)d_in[3];
  const float* bq = (const float*)d_in[4];
  const float* Wk = (const float*)d_in[5];
  const float* bk = (const float*)d_in[6];
  const float* Wv = (const float*)d_in[7];
  const float* bv = (const float*)d_in[8];
  const float* Wo = (const float*)d_in[9];
  const float* bo = (const float*)d_in[10];

  float* out  = (float*)d_out;
  float* attn = out + (long)4 * 1024 * 1024;  // output first, then attn_weights

  // workspace layout (48 MB total)
  char* ws = (char*)d_ws;
  const long MB = 1 << 20;
  u16* WQb = (u16*)(ws + 0 * MB);
  u16* WKb = (u16*)(ws + 2 * MB);
  u16* WVb = (u16*)(ws + 4 * MB);
  u16* WOb = (u16*)(ws + 6 * MB);
  u16* QP  = (u16*)(ws + 8 * MB);   // (B,H,S,64) bf16
  u16* KP  = (u16*)(ws + 16 * MB);
  u16* VP  = (u16*)(ws + 24 * MB);
  u16* VPT = (u16*)(ws + 32 * MB);  // (B,H,64,S)
  u16* AO  = (u16*)(ws + 40 * MB);  // (B,S,1024) bf16

  // 1) weights -> bf16
  k_f2bf<<<1024, 256, 0, stream>>>(Wq, WQb, 1 << 20);
  k_f2bf<<<1024, 256, 0, stream>>>(Wk, WKb, 1 << 20);
  k_f2bf<<<1024, 256, 0, stream>>>(Wv, WVb, 1 << 20);
  k_f2bf<<<1024, 256, 0, stream>>>(Wo, WOb, 1 << 20);

  // 2) projections: (4096x1024) @ W^T + b -> split-head bf16
  dim3 gP(32, 8, 1);
  k_gemm_bt<128, 128, true, 1, true><<<gP, 256, 0, stream>>>(
      Q,  WQb, bq, QP, 1024, 1024, 1024, 0, 0, 0, 0, 1.0f);
  k_gemm_bt<128, 128, true, 1, true><<<gP, 256, 0, stream>>>(
      Kx, WKb, bk, KP, 1024, 1024, 1024, 0, 0, 0, 0, 1.0f);
  k_gemm_bt<128, 128, true, 1, true><<<gP, 256, 0, stream>>>(
      V,  WVb, bv, VP, 1024, 1024, 1024, 0, 0, 0, 0, 1.0f);

  // 3) V transpose per head
  k_transpose_v<<<dim3(32, 32), 256, 0, stream>>>(VP, VPT);

  // 4) scores = q @ k^T * 1/8  -> attn region (fp32), then softmax in place
  dim3 gS(16, 16, 32);
  k_gemm_bt<128, 128, false, 0, false><<<gS, 256, 0, stream>>>(
      QP, KP, nullptr, attn, 64, 64, 64, 2048,
      131072, 131072, 4194304, 0.125f);
  k_softmax<<<16384, 256, 0, stream>>>(attn);

  // 5) PV: attn (fp32, converted in staging) @ vpT^T -> AO bf16, then out proj
  dim3 gPV(8, 1, 32);
  k_gemm_bt<256, 64, true, 2, false><<<gPV, 256, 0, stream>>>(
      attn, VPT, nullptr, AO, 2048, 2048, 2048, 0,
      4194304, 131072, 0, 1.0f);

  dim3 gO(32, 8, 1);
  k_gemm_bt<128, 128, false, 0, true><<<gO, 256, 0, stream>>>(
      AO, WOb, bo, out, 1024, 1024, 1024, 1024, 0, 0, 0, 1.0f);
}

// Round 2
// 450.301 us; speedup vs baseline: 1.4894x; 1.4894x over previous
//
#include <hip/hip_runtime.h>

typedef unsigned short u16;
typedef unsigned int u32;
typedef float f32x4 __attribute__((ext_vector_type(4)));
typedef __bf16 bf16x8 __attribute__((ext_vector_type(8)));
typedef unsigned short u16x8 __attribute__((ext_vector_type(8)));
typedef unsigned short u16x4 __attribute__((ext_vector_type(4)));

#define DEV static __device__ __forceinline__

DEV u16 f2bf(float f) {
  union { float f; u32 u; } x; x.f = f;
  u32 r = x.u + 0x7FFFu + ((x.u >> 16) & 1u);
  return (u16)(r >> 16);
}

DEV f32x4 mfma16(bf16x8 a, bf16x8 b, f32x4 c) {
  return __builtin_amdgcn_mfma_f32_16x16x32_bf16(a, b, c, 0, 0, 0);
}

// ---- fp32 -> bf16 convert (weights) ----
__global__ __launch_bounds__(256) void k_f2bf(const float* __restrict__ in,
                                              u16* __restrict__ out, int n) {
  int i = (blockIdx.x * 256 + threadIdx.x) * 4;
  if (i >= n) return;
  f32x4 v = *(const f32x4*)(in + i);
  u16x4 o;
#pragma unroll
  for (int j = 0; j < 4; ++j) o[j] = f2bf(v[j]);
  *(u16x4*)(out + i) = o;
}

// ---- generic BT-GEMM: C[m][n] = scale * sum_k A[m][k] * B[n][k] (+ bias[n]) ----
template<int BM, int BN, bool A_F32, int OUT_MODE, bool HAS_BIAS>
__global__ __launch_bounds__(256) void k_gemm_bt(
    const void* __restrict__ Aptr, const u16* __restrict__ Bptr,
    const float* __restrict__ bias, void* __restrict__ Cptr,
    int K, int lda, int ldb, int ldc,
    long sA, long sB, long sC, float scale)
{
  constexpr int WM = BM / 64, WN = BN / 64;
  static_assert(WM * WN == 4, "4 waves");
  constexpr int LDSK = 40;
  __shared__ u16 a_lds[BM * LDSK];
  __shared__ u16 b_lds[BN * LDSK];

  const int t = threadIdx.x;
  const int lane = t & 63, wid = t >> 6;
  const int wm = wid % WM, wn = wid / WM;
  const long a_off = (long)blockIdx.z * sA + (long)blockIdx.x * BM * lda;
  const long b_off = (long)blockIdx.z * sB + (long)blockIdx.y * BN * ldb;
  const float* __restrict__ Af = (const float*)Aptr;
  const u16*  __restrict__ Ab = (const u16*)Aptr;

  f32x4 acc[4][4] = {};
  const int fr = lane & 15, kq = (lane >> 4) * 8;

  for (int kt = 0; kt < K; kt += 32) {
#pragma unroll
    for (int i = 0; i < BM / 64; ++i) {
      int idx = t + i * 256;
      int row = idx >> 2, k0 = (idx & 3) * 8;
      long g = a_off + (long)row * lda + kt + k0;
      u16x8 stg;
      if (A_F32) {
        f32x4 v0 = *(const f32x4*)(Af + g);
        f32x4 v1 = *(const f32x4*)(Af + g + 4);
#pragma unroll
        for (int j = 0; j < 4; ++j) { stg[j] = f2bf(v0[j]); stg[4 + j] = f2bf(v1[j]); }
      } else {
        stg = *(const u16x8*)(Ab + g);
      }
      *(u16x8*)&a_lds[row * LDSK + k0] = stg;
    }
#pragma unroll
    for (int i = 0; i < BN / 64; ++i) {
      int idx = t + i * 256;
      int row = idx >> 2, k0 = (idx & 3) * 8;
      long g = b_off + (long)row * ldb + kt + k0;
      *(u16x8*)&b_lds[row * LDSK + k0] = *(const u16x8*)(Bptr + g);
    }
    __syncthreads();

    bf16x8 af[4], bf[4];
#pragma unroll
    for (int mi = 0; mi < 4; ++mi)
      af[mi] = *(const bf16x8*)&a_lds[(wm * 64 + mi * 16 + fr) * LDSK + kq];
#pragma unroll
    for (int ni = 0; ni < 4; ++ni)
      bf[ni] = *(const bf16x8*)&b_lds[(wn * 64 + ni * 16 + fr) * LDSK + kq];
#pragma unroll
    for (int mi = 0; mi < 4; ++mi)
#pragma unroll
      for (int ni = 0; ni < 4; ++ni)
        acc[mi][ni] = mfma16(af[mi], bf[ni], acc[mi][ni]);
    __syncthreads();
  }

  const int r4 = (lane >> 4) * 4, cc = lane & 15;
#pragma unroll
  for (int mi = 0; mi < 4; ++mi)
#pragma unroll
  for (int ni = 0; ni < 4; ++ni)
#pragma unroll
  for (int rg = 0; rg < 4; ++rg) {
    int row = blockIdx.x * BM + wm * 64 + mi * 16 + r4 + rg;
    int col = blockIdx.y * BN + wn * 64 + ni * 16 + cc;
    float v = acc[mi][ni][rg] * scale;
    if (HAS_BIAS) v += bias[col];
    if (OUT_MODE == 0) {
      ((float*)Cptr)[(long)blockIdx.z * sC + (long)row * ldc + col] = v;
    } else {
      int b = row >> 11, s = row & 2047, h = col >> 6, d = col & 63;
      ((u16*)Cptr)[(((long)(b * 16 + h) * 2048 + s) << 6) + d] = f2bf(v);
    }
  }
}

// ---- per-head V transpose: (bh, S=2048, 64) -> (bh, 64, S=2048), bf16 ----
__global__ __launch_bounds__(256) void k_transpose_v(const u16* __restrict__ vp,
                                                     u16* __restrict__ vpt) {
  __shared__ u16 tile[64][72];
  const int t = threadIdx.x;
  const long base = (long)blockIdx.y * (2048 * 64);
  const int s0 = blockIdx.x * 64;
#pragma unroll
  for (int i = 0; i < 2; ++i) {
    int idx = t + i * 256;
    int s = idx >> 3, c = (idx & 7) * 8;
    u16x8 v = *(const u16x8*)&vp[base + (long)(s0 + s) * 64 + c];
    *(u16x8*)&tile[s][c] = v;
  }
  __syncthreads();
  const long obase = (long)blockIdx.y * (64 * 2048);
#pragma unroll
  for (int i = 0; i < 2; ++i) {
    int idx = t + i * 256;
    int d = idx >> 3, c = (idx & 7) * 8;
    u16x8 v;
#pragma unroll
    for (int j = 0; j < 8; ++j) v[j] = tile[c + j][d];
    *(u16x8*)&vpt[obase + (long)d * 2048 + s0 + c] = v;
  }
}

// ---- fused attention: scores + softmax + attn-write + PV ----
// grid: x = 16 (128-row q blocks), z = 32 (b*16+h). 256 threads = 4 waves.
// Wave w owns q rows [w*32, w*32+32). Two-pass online softmax:
//   pass A: stream K tiles, compute row max m and denom l (exact).
//   pass B: recompute scores, write normalized P (f32) to attn once,
//           stage P bf16 in swizzled LDS, accumulate PV via MFMA.
__global__ __launch_bounds__(256, 3) void k_fused_attn(
    const u16* __restrict__ QP, const u16* __restrict__ KP,
    const u16* __restrict__ VPT, float* __restrict__ attn,
    u16* __restrict__ AO)
{
  constexpr int LDK = 72;   // k_lds u16 stride (144 B)
  constexpr int LDV = 136;  // vt_lds u16 stride (272 B)
  __shared__ u16 k_lds[128 * LDK];    // 18432 B
  __shared__ u16 vt_lds[64 * LDV];    // 17408 B
  __shared__ u16 p_lds[4 * 16 * 128]; // 16384 B (per-wave 4 KB, XOR-swizzled)

  const int t = threadIdx.x, lane = t & 63, w = t >> 6;
  const int fr = lane & 15, g = lane >> 4;
  const int zz = blockIdx.z;            // b*16+h
  const int b = zz >> 4, h = zz & 15;
  const int q0 = blockIdx.x * 128;
  const long headQK = (long)zz * (2048 * 64);
  const long headVT = (long)zz * (64 * 2048);
  const float scale = 0.125f;

  // Q fragments in registers (persist across both passes)
  bf16x8 aq[2][2];
#pragma unroll
  for (int mi = 0; mi < 2; ++mi)
#pragma unroll
    for (int kk = 0; kk < 2; ++kk)
      aq[mi][kk] = *(const bf16x8*)&QP[headQK +
          (long)(q0 + w * 32 + mi * 16 + fr) * 64 + kk * 32 + g * 8];

  float m[2][4], l[2][4];
#pragma unroll
  for (int mi = 0; mi < 2; ++mi)
#pragma unroll
    for (int rg = 0; rg < 4; ++rg) { m[mi][rg] = -1e30f; l[mi][rg] = 0.f; }

  // ---------------- pass A: row stats ----------------
  for (int kt = 0; kt < 16; ++kt) {
    __syncthreads();
#pragma unroll
    for (int i = 0; i < 4; ++i) {
      int idx = t + i * 256;
      int r = idx >> 3, c = (idx & 7) * 8;
      *(u16x8*)&k_lds[r * LDK + c] =
          *(const u16x8*)&KP[headQK + (long)(kt * 128 + r) * 64 + c];
    }
    __syncthreads();

#pragma unroll
    for (int mi = 0; mi < 2; ++mi) {
      float e[8][4];
#pragma unroll
      for (int ni = 0; ni < 8; ++ni) {
        f32x4 c = {};
#pragma unroll
        for (int kk = 0; kk < 2; ++kk) {
          bf16x8 bk = *(const bf16x8*)&k_lds[(ni * 16 + fr) * LDK + kk * 32 + g * 8];
          c = mfma16(aq[mi][kk], bk, c);
        }
#pragma unroll
        for (int rg = 0; rg < 4; ++rg) e[ni][rg] = c[rg] * scale;
      }
#pragma unroll
      for (int rg = 0; rg < 4; ++rg) {
        float tv = e[0][rg];
#pragma unroll
        for (int ni = 1; ni < 8; ++ni) tv = fmaxf(tv, e[ni][rg]);
#pragma unroll
        for (int off = 1; off < 16; off <<= 1) tv = fmaxf(tv, __shfl_xor(tv, off));
        float mn = fmaxf(m[mi][rg], tv);
        float corr = __expf(m[mi][rg] - mn);
        float s = 0.f;
#pragma unroll
        for (int ni = 0; ni < 8; ++ni) s += __expf(e[ni][rg] - mn);
#pragma unroll
        for (int off = 1; off < 16; off <<= 1) s += __shfl_xor(s, off);
        l[mi][rg] = l[mi][rg] * corr + s;
        m[mi][rg] = mn;
      }
    }
  }

  float invl[2][4];
#pragma unroll
  for (int mi = 0; mi < 2; ++mi)
#pragma unroll
    for (int rg = 0; rg < 4; ++rg) invl[mi][rg] = 1.0f / l[mi][rg];

  f32x4 acc[2][4] = {};
  char* pw = (char*)&p_lds[w * 2048];  // 4 KB per wave: 16 rows x 128 cols bf16

  // ---------------- pass B: attn write + PV ----------------
  for (int kt = 0; kt < 16; ++kt) {
    __syncthreads();
#pragma unroll
    for (int i = 0; i < 4; ++i) {
      int idx = t + i * 256;
      int r = idx >> 3, c = (idx & 7) * 8;
      *(u16x8*)&k_lds[r * LDK + c] =
          *(const u16x8*)&KP[headQK + (long)(kt * 128 + r) * 64 + c];
    }
#pragma unroll
    for (int i = 0; i < 4; ++i) {
      int idx = t + i * 256;
      int d = idx >> 4, c = (idx & 15) * 8;
      *(u16x8*)&vt_lds[d * LDV + c] =
          *(const u16x8*)&VPT[headVT + (long)d * 2048 + kt * 128 + c];
    }
    __syncthreads();

#pragma unroll
    for (int mi = 0; mi < 2; ++mi) {
      // recompute scores, write attn, fill this wave's P tile (16 rows)
#pragma unroll
      for (int ni = 0; ni < 8; ++ni) {
        f32x4 c = {};
#pragma unroll
        for (int kk = 0; kk < 2; ++kk) {
          bf16x8 bk = *(const bf16x8*)&k_lds[(ni * 16 + fr) * LDK + kk * 32 + g * 8];
          c = mfma16(aq[mi][kk], bk, c);
        }
#pragma unroll
        for (int rg = 0; rg < 4; ++rg) {
          int r16 = g * 4 + rg;
          float p = __expf(c[rg] * scale - m[mi][rg]) * invl[mi][rg];
          attn[((long)zz * 2048 + q0 + w * 32 + mi * 16 + r16) * 2048 +
               kt * 128 + ni * 16 + fr] = p;
          int byte = (r16 << 8) + ((ni * 16 + fr) << 1);
          byte ^= (r16 & 7) << 4;
          *(u16*)(pw + byte) = f2bf(p);
        }
      }
      // PV for this mi: acc += P(16x128) @ VT(64x128)^T
#pragma unroll
      for (int kk = 0; kk < 4; ++kk) {
        int byte = (fr << 8) + ((kk * 32 + g * 8) << 1);
        byte ^= (fr & 7) << 4;
        bf16x8 pa = *(const bf16x8*)(pw + byte);
#pragma unroll
        for (int di = 0; di < 4; ++di) {
          bf16x8 bv = *(const bf16x8*)&vt_lds[(di * 16 + fr) * LDV + kk * 32 + g * 8];
          acc[mi][di] = mfma16(pa, bv, acc[mi][di]);
        }
      }
    }
  }

  // epilogue -> AO (b, s, 1024) bf16
#pragma unroll
  for (int mi = 0; mi < 2; ++mi)
#pragma unroll
  for (int di = 0; di < 4; ++di)
#pragma unroll
  for (int rg = 0; rg < 4; ++rg) {
    int row = q0 + w * 32 + mi * 16 + g * 4 + rg;
    AO[((long)b * 2048 + row) * 1024 + h * 64 + di * 16 + fr] =
        f2bf(acc[mi][di][rg]);
  }
}

extern "C" void kernel_launch(void* const* d_in, const int* in_sizes, int n_in,
                              void* d_out, int out_size, void* d_ws, size_t ws_size,
                              hipStream_t stream) {
  const float* Q  = (const float*)d_in[0];
  const float* Kx = (const float*)d_in[1];
  const float* V  = (const float*)d_in[2];
  const float* Wq = (const float*)d_in[3];
  const float* bq = (const float*)d_in[4];
  const float* Wk = (const float*)d_in[5];
  const float* bk = (const float*)d_in[6];
  const float* Wv = (const float*)d_in[7];
  const float* bv = (const float*)d_in[8];
  const float* Wo = (const float*)d_in[9];
  const float* bo = (const float*)d_in[10];

  float* out  = (float*)d_out;
  float* attn = out + (long)4 * 1024 * 1024;

  char* ws = (char*)d_ws;
  const long MB = 1 << 20;
  u16* WQb = (u16*)(ws + 0 * MB);
  u16* WKb = (u16*)(ws + 2 * MB);
  u16* WVb = (u16*)(ws + 4 * MB);
  u16* WOb = (u16*)(ws + 6 * MB);
  u16* QP  = (u16*)(ws + 8 * MB);   // (B,H,S,64) bf16
  u16* KP  = (u16*)(ws + 16 * MB);
  u16* VP  = (u16*)(ws + 24 * MB);
  u16* VPT = (u16*)(ws + 32 * MB);  // (B,H,64,S)
  u16* AO  = (u16*)(ws + 40 * MB);  // (B,S,1024) bf16

  k_f2bf<<<1024, 256, 0, stream>>>(Wq, WQb, 1 << 20);
  k_f2bf<<<1024, 256, 0, stream>>>(Wk, WKb, 1 << 20);
  k_f2bf<<<1024, 256, 0, stream>>>(Wv, WVb, 1 << 20);
  k_f2bf<<<1024, 256, 0, stream>>>(Wo, WOb, 1 << 20);

  dim3 gP(32, 8, 1);
  k_gemm_bt<128, 128, true, 1, true><<<gP, 256, 0, stream>>>(
      Q,  WQb, bq, QP, 1024, 1024, 1024, 0, 0, 0, 0, 1.0f);
  k_gemm_bt<128, 128, true, 1, true><<<gP, 256, 0, stream>>>(
      Kx, WKb, bk, KP, 1024, 1024, 1024, 0, 0, 0, 0, 1.0f);
  k_gemm_bt<128, 128, true, 1, true><<<gP, 256, 0, stream>>>(
      V,  WVb, bv, VP, 1024, 1024, 1024, 0, 0, 0, 0, 1.0f);

  k_transpose_v<<<dim3(32, 32), 256, 0, stream>>>(VP, VPT);

  k_fused_attn<<<dim3(16, 1, 32), 256, 0, stream>>>(QP, KP, VPT, attn, AO);

  dim3 gO(32, 8, 1);
  k_gemm_bt<128, 128, false, 0, true><<<gO, 256, 0, stream>>>(
      AO, WOb, bo, out, 1024, 1024, 1024, 1024, 0, 0, 0, 1.0f);
}